// Round 9
// baseline (4888.767 us; speedup 1.0000x reference)
//
#include <hip/hip_runtime.h>
#include <stdint.h>

#define HID 512

typedef short bf16x8 __attribute__((ext_vector_type(8)));
typedef short short8v __attribute__((ext_vector_type(8)));
typedef float f32x4 __attribute__((ext_vector_type(4)));

__device__ __forceinline__ unsigned short f2bf_rne(float f) {
  unsigned u = __float_as_uint(f);
  unsigned r = u + 0x7fffu + ((u >> 16) & 1u);
  return (unsigned short)(r >> 16);
}
__device__ __forceinline__ float bf2f(unsigned short u) {
  return __uint_as_float(((unsigned)u) << 16);
}

__device__ __forceinline__ void gload_lds16(const void* g, void* l) {
  auto gp = reinterpret_cast<const __attribute__((address_space(1))) unsigned int*>(
      (unsigned long long)(uintptr_t)g);
  auto lp = reinterpret_cast<__attribute__((address_space(3))) unsigned int*>(
      (unsigned int)(uintptr_t)l);
  __builtin_amdgcn_global_load_lds(gp, lp, 16, 0, 0);
}

// ---------------- pack kernels ----------------
// pack4: W [512 k][512 n] -> [xb4][kt16][pl2][s4][128 n][8 k]  (1 MB)
__global__ void pack4(const float* __restrict__ W, short* __restrict__ out) {
  int id = blockIdx.x * 256 + threadIdx.x;                 // 2^19
  int e = id & 7, r = (id >> 3) & 127, s = (id >> 10) & 3, pl = (id >> 12) & 1,
      kt = (id >> 13) & 15, xb = id >> 17;
  int k = kt * 32 + s * 8 + e, n = xb * 128 + r;
  float w = W[(size_t)k * 512 + n];
  unsigned short h = f2bf_rne(w);
  out[id] = pl ? (short)f2bf_rne(w - bf2f(h)) : (short)h;
}

// packW: P1 rows 512..1023 -> [kt16][pl2][s4][512 n][8 k]  (1 MB, full width)
__global__ void packW(const float* __restrict__ P1, short* __restrict__ out) {
  int id = blockIdx.x * 256 + threadIdx.x;                 // 2^19
  int e = id & 7, r = (id >> 3) & 511, s = (id >> 12) & 3, pl = (id >> 14) & 1,
      kt = id >> 15;
  int k = kt * 32 + s * 8 + e;
  float w = P1[(size_t)(512 + k) * 512 + r];
  unsigned short h = f2bf_rne(w);
  out[id] = pl ? (short)f2bf_rne(w - bf2f(h)) : (short)h;
}

// split x -> hi/lo tile image [rb][kt16][pl2][s4][128][8]
__global__ void split_x_img(const float* __restrict__ x, short* __restrict__ img,
                            int NN, int total) {
  int id = blockIdx.x * 256 + threadIdx.x;
  if (id >= total) return;
  int n = id >> 6, kc = id & 63;
  int ns = n < NN ? n : NN - 1;
  const f32x4* xp = reinterpret_cast<const f32x4*>(x + (size_t)ns * 512 + kc * 8);
  f32x4 a = xp[0], b = xp[1];
  short8v h, l;
#pragma unroll
  for (int q = 0; q < 4; ++q) {
    unsigned short ha = f2bf_rne(a[q]);
    h[q] = (short)ha; l[q] = (short)f2bf_rne(a[q] - bf2f(ha));
    unsigned short hb = f2bf_rne(b[q]);
    h[q + 4] = (short)hb; l[q + 4] = (short)f2bf_rne(b[q] - bf2f(hb));
  }
  size_t base = ((size_t)((n >> 7) * 16 + (kc >> 2)) * 2) * 4096 + (kc & 3) * 1024 + (n & 127) * 8;
  *reinterpret_cast<short8v*>(img + base) = h;
  *reinterpret_cast<short8v*>(img + base + 4096) = l;
}

__global__ void init_out_kernel(float* __restrict__ out, const float* __restrict__ p3b, int n) {
  int id = blockIdx.x * 256 + threadIdx.x;
  if (id < n) out[id] = p3b[0];
}

// ---------------- GEMM ----------------
// EPI: 0 relu+bias -> image | 1 relu+bias+residual(LDS) -> image |
//      2 fused P2 relu + P3 dot -> score | 3 bias, no relu -> UV rows |
//      4 no bias, no relu -> UV rows
// GATHER: A built in-stage as relu(U[s]+V[d]) from hi/lo UV rows.
// WN: wave-columns (2 -> 128-col block, 256 thr, 5 blocks/CU;
//                   8 -> 512-col block, 1024 thr, in-place-safe fallback).
template <int EPI, bool GATHER, int WN>
__global__ __launch_bounds__(WN * 128, WN == 2 ? 5 : 8) void gemm4(
    const short* A, const short* A2, const short* __restrict__ B,
    const float* __restrict__ bias, const float* __restrict__ p3,
    const int* __restrict__ isrc, const int* __restrict__ idst,
    short* C, float* __restrict__ score, int M, int yb, int nys) {
  constexpr int BSH = 4096 * WN;            // B lds shorts (8192 / 32768)
  constexpr int BSTR = 512 * WN;            // B slab stride (1024 / 4096)
  constexpr int BPL = 2048 * WN;            // B plane stride (4096 / 16384)
  __shared__ __align__(16) short lds[8192 + BSH];

  const int tid = threadIdx.x;
  const int lane = tid & 63, wid = tid >> 6;
  const int wr = (WN == 2) ? (wid >> 1) : (wid >> 3);
  const int wc = (WN == 2) ? (wid & 1) : (wid & 7);
  const int l15 = lane & 15, lh = lane >> 4;

  // XCD swizzle: 4 x-siblings of a y share (g mod 8) -> same XCD; y streams per XCD
  const int g = blockIdx.x;
  const int xcd = g & 7, rr_ = g >> 3;
  const int x = (WN == 2) ? (rr_ & 3) : 0;
  const int slot = (WN == 2) ? (rr_ >> 2) : rr_;
  const int y = xcd * nys + slot;
  if (y >= yb) return;
  const int m0 = y << 7;
  const int n0 = x << 7;

  const size_t aBase0 = (size_t)y * 16 * 8192;

  int urow = 0, vrow = 0;
  if constexpr (GATHER) {
    int e = m0 + (tid >> 1); if (e > M - 1) e = M - 1;
    urow = isrc[e]; vrow = idst[e];
  }

  auto stage = [&](int kt) {
    const short* ab = A + aBase0 + (size_t)kt * 8192;
    const short* bb = B + (size_t)((WN == 2) ? (x * 16 + kt) : kt) * BSH;
    if constexpr (WN == 2) {
#pragma unroll
      for (int p = 0; p < 4; ++p) gload_lds16(ab + p * 2048 + tid * 8, lds + p * 2048 + tid * 8);
#pragma unroll
      for (int p = 0; p < 4; ++p) gload_lds16(bb + p * 2048 + tid * 8, lds + 8192 + p * 2048 + tid * 8);
    } else {
      gload_lds16(ab + tid * 8, lds + tid * 8);
#pragma unroll
      for (int p = 0; p < 4; ++p) gload_lds16(bb + p * 8192 + tid * 8, lds + 8192 + p * 8192 + tid * 8);
    }
  };

  auto stageG = [&](int kt) {
    const short* bb = B + (size_t)(x * 16 + kt) * 8192;
#pragma unroll
    for (int p = 0; p < 4; ++p) gload_lds16(bb + p * 2048 + tid * 8, lds + 8192 + p * 2048 + tid * 8);
    const int kh = tid & 1;
    const size_t ub = (size_t)(urow >> 7) * 131072 + (urow & 127) * 1024 + kt * 32 + kh * 16;
    const size_t vb = (size_t)(vrow >> 7) * 131072 + (vrow & 127) * 1024 + kt * 32 + kh * 16;
    short8v uh0 = *(const short8v*)(A + ub),        uh1 = *(const short8v*)(A + ub + 8);
    short8v ul0 = *(const short8v*)(A + ub + 512),  ul1 = *(const short8v*)(A + ub + 520);
    short8v vh0 = *(const short8v*)(A2 + vb),       vh1 = *(const short8v*)(A2 + vb + 8);
    short8v vl0 = *(const short8v*)(A2 + vb + 512), vl1 = *(const short8v*)(A2 + vb + 520);
    short8v zh0, zh1, zl0, zl1;
#pragma unroll
    for (int q = 0; q < 8; ++q) {
      float u0 = bf2f((unsigned short)uh0[q]) + bf2f((unsigned short)ul0[q]);
      float v0 = bf2f((unsigned short)vh0[q]) + bf2f((unsigned short)vl0[q]);
      float z0 = fmaxf(u0 + v0, 0.f);
      unsigned zb0 = __float_as_uint(z0);
      zh0[q] = (short)(zb0 >> 16);
      zl0[q] = (short)f2bf_rne(z0 - __uint_as_float(zb0 & 0xffff0000u));
      float u1 = bf2f((unsigned short)uh1[q]) + bf2f((unsigned short)ul1[q]);
      float v1 = bf2f((unsigned short)vh1[q]) + bf2f((unsigned short)vl1[q]);
      float z1 = fmaxf(u1 + v1, 0.f);
      unsigned zb1 = __float_as_uint(z1);
      zh1[q] = (short)(zb1 >> 16);
      zl1[q] = (short)f2bf_rne(z1 - __uint_as_float(zb1 & 0xffff0000u));
    }
    const int da = kh * 2048 + (tid >> 1) * 8;   // [s=2kh][r][8], s-stride 1024
    *reinterpret_cast<short8v*>(lds + da) = zh0;
    *reinterpret_cast<short8v*>(lds + da + 1024) = zh1;
    *reinterpret_cast<short8v*>(lds + 4096 + da) = zl0;
    *reinterpret_cast<short8v*>(lds + 4096 + da + 1024) = zl1;
  };

  f32x4 acc[4][4];
#pragma unroll
  for (int i = 0; i < 4; ++i)
#pragma unroll
    for (int j = 0; j < 4; ++j)
#pragma unroll
      for (int r = 0; r < 4; ++r) acc[i][j][r] = 0.f;

  [[maybe_unused]] float res[4][4][4];
  if constexpr (EPI == 1) {
#pragma unroll
    for (int i = 0; i < 4; ++i)
#pragma unroll
      for (int j = 0; j < 4; ++j)
#pragma unroll
        for (int r = 0; r < 4; ++r) res[i][j][r] = 0.f;
  }

  auto compute = [&]() {
    bf16x8 ah[4], al[4];
#pragma unroll
    for (int i = 0; i < 4; ++i) {
      const int ro = lh * 1024 + (wr * 64 + i * 16 + l15) * 8;
      ah[i] = *reinterpret_cast<const bf16x8*>(lds + ro);
      al[i] = *reinterpret_cast<const bf16x8*>(lds + 4096 + ro);
    }
#pragma unroll
    for (int j = 0; j < 4; ++j) {
      const int co = 8192 + lh * BSTR + (wc * 64 + j * 16 + l15) * 8;
      bf16x8 bh = *reinterpret_cast<const bf16x8*>(lds + co);
      bf16x8 bl = *reinterpret_cast<const bf16x8*>(lds + co + BPL);
#pragma unroll
      for (int i = 0; i < 4; ++i) {
        acc[i][j] = __builtin_amdgcn_mfma_f32_16x16x32_bf16(ah[i], bh, acc[i][j], 0, 0, 0);
        acc[i][j] = __builtin_amdgcn_mfma_f32_16x16x32_bf16(ah[i], bl, acc[i][j], 0, 0, 0);
        acc[i][j] = __builtin_amdgcn_mfma_f32_16x16x32_bf16(al[i], bh, acc[i][j], 0, 0, 0);
      }
    }
  };

  // K-loop: single buffer, 2 barriers per step; co-resident blocks hide drains
  for (int kt = 0; kt < 16; ++kt) {
    if (kt) __syncthreads();
    if constexpr (GATHER) stageG(kt); else stage(kt);
    __syncthreads();
    compute();
    if constexpr (EPI == 1) {
      // harvest residual frags from the A-tile while it's still in LDS:
      // k-range of this tile covers output cols when kt_loc = kt-4x in [0,4)
      // and (kt_loc>>1)==wc; provides fj pair {2*(kt_loc&1), 2*(kt_loc&1)+1}.
      const int ktl = kt - x * 4;
      if (ktl >= 0 && ktl < 4 && (ktl >> 1) == wc) {
        const int fjh = ktl & 1;
#pragma unroll
        for (int fq = 0; fq < 2; ++fq) {
          const int fj = fjh * 2 + fq;
          const int c32 = fq * 16 + l15;           // (fj&1)*16 + l15
          const int so = (c32 >> 3) * 1024 + (c32 & 7);
#pragma unroll
          for (int fi = 0; fi < 4; ++fi)
#pragma unroll
            for (int r = 0; r < 4; ++r) {
              const int row = wr * 64 + fi * 16 + lh * 4 + r;
              res[fi][fj][r] = bf2f((unsigned short)lds[so + row * 8]) +
                               bf2f((unsigned short)lds[4096 + so + row * 8]);
            }
        }
      }
    }
  }

  // ---------------- epilogue ----------------
  float bj[4], pj[4];
#pragma unroll
  for (int j = 0; j < 4; ++j) {
    const int col = n0 + wc * 64 + j * 16 + l15;
    bj[j] = (EPI == 4) ? 0.f : bias[col];
    pj[j] = (EPI == 2) ? p3[col] : 0.f;
  }

  if constexpr (EPI == 2) {
#pragma unroll
    for (int fi = 0; fi < 4; ++fi)
#pragma unroll
      for (int r = 0; r < 4; ++r) {
        float pS = 0.f;
#pragma unroll
        for (int fj = 0; fj < 4; ++fj)
          pS += fmaxf(acc[fi][fj][r] + bj[fj], 0.f) * pj[fj];
        pS += __shfl_xor(pS, 1);
        pS += __shfl_xor(pS, 2);
        pS += __shfl_xor(pS, 4);
        pS += __shfl_xor(pS, 8);
        const int row = m0 + wr * 64 + fi * 16 + lh * 4 + r;
        if (l15 == 0 && row < M) atomicAdd(&score[row], pS);
      }
  } else {
#pragma unroll
    for (int fi = 0; fi < 4; ++fi)
#pragma unroll
      for (int fj = 0; fj < 4; ++fj) {
        const int col = n0 + wc * 64 + fj * 16 + l15;
#pragma unroll
        for (int r = 0; r < 4; ++r) {
          const int row = m0 + wr * 64 + fi * 16 + lh * 4 + r;
          if (row >= M) continue;
          float v = acc[fi][fj][r] + bj[fj];
          if constexpr (EPI == 0 || EPI == 1) v = fmaxf(v, 0.f);
          if constexpr (EPI == 0 || EPI == 1) {
            const size_t ix = ((size_t)(y * 16 + (col >> 5)) * 2) * 4096 +
                              ((col >> 3) & 3) * 1024 + (row & 127) * 8 + (col & 7);
            if constexpr (EPI == 1) v += res[fi][fj][r];
            unsigned short h = f2bf_rne(v);
            C[ix] = (short)h;
            C[ix + 4096] = (short)f2bf_rne(v - bf2f(h));
          } else {  // EPI 3/4: UV row layout [rb][r][hi512|lo512]
            const size_t ux = (size_t)y * 131072 + (row & 127) * 1024 + col;
            unsigned short h = f2bf_rne(v);
            C[ux] = (short)h;
            C[ux + 512] = (short)f2bf_rne(v - bf2f(h));
          }
        }
      }
  }
}

extern "C" void kernel_launch(void* const* d_in, const int* in_sizes, int n_in,
                              void* d_out, int out_size, void* d_ws, size_t ws_size,
                              hipStream_t stream) {
  (void)n_in; (void)out_size;
  const float* x      = (const float*)d_in[0];
  const int* pos_src  = (const int*)d_in[1];
  const int* pos_dst  = (const int*)d_in[2];
  const int* neg_src  = (const int*)d_in[3];
  const int* neg_dst  = (const int*)d_in[4];
  const float* W1 = (const float*)d_in[5];
  const float* b1 = (const float*)d_in[6];
  const float* W2 = (const float*)d_in[7];
  const float* b2 = (const float*)d_in[8];
  const float* Wo = (const float*)d_in[9];
  const float* bo = (const float*)d_in[10];
  const float* P1w = (const float*)d_in[11];
  const float* P1b = (const float*)d_in[12];
  const float* P2w = (const float*)d_in[13];
  const float* P2b = (const float*)d_in[14];
  const float* P3w = (const float*)d_in[15];
  const float* P3b = (const float*)d_in[16];

  const int NN = in_sizes[0] / HID;  // 100000
  const int E = in_sizes[1];         // 100000
  float* out = (float*)d_out;

  const int yb = (NN + 127) / 128;           // 782 (== (E+127)/128)
  const int nys = (yb + 7) / 8;              // 98
  const size_t IMG = (size_t)yb * 131072;    // shorts per activation buffer

  // ws layout: [6 weight packs 1MB each][A0][A1][A2 if it fits]
  short* wp = (short*)d_ws;
  short* Wp1  = wp; wp += 524288;
  short* Wp2  = wp; wp += 524288;
  short* Wpo  = wp; wp += 524288;
  short* Wp2p = wp; wp += 524288;
  short* WpU  = wp; wp += 524288;            // P1 top (xb4 images)
  short* WpV  = wp; wp += 524288;            // P1 bottom
  short* A0 = wp;                            // x-img -> h2-img -> U (UV rows)
  short* A1 = A0 + IMG;                      // h1-img -> H-img (-> V in fallback)
  short* A2 = A1 + IMG;                      // V (UV rows) when ws permits
  const bool use3 = ws_size >= (size_t)(6 * 524288 + 3 * IMG) * sizeof(short);
  short* Vbuf = use3 ? A2 : A1;

  pack4<<<2048, 256, 0, stream>>>(W1, Wp1);
  pack4<<<2048, 256, 0, stream>>>(W2, Wp2);
  pack4<<<2048, 256, 0, stream>>>(Wo, Wpo);
  pack4<<<2048, 256, 0, stream>>>(P2w, Wp2p);
  pack4<<<2048, 256, 0, stream>>>(P1w, WpU);
  if (use3) pack4<<<2048, 256, 0, stream>>>(P1w + (size_t)512 * 512, WpV);
  else      packW<<<2048, 256, 0, stream>>>(P1w, WpV);
  const int totX = yb * 128 * 64;
  split_x_img<<<(totX + 255) / 256, 256, 0, stream>>>(x, A0, NN, totX);
  init_out_kernel<<<(2 * E + 255) / 256, 256, 0, stream>>>(out, P3b, 2 * E);

  dim3 g4(8 * nys * 4), gW(8 * nys), b256(256), b1024(1024);

  // encoder: h1 = relu(x@W1+b1); h2 = relu(h1@W2+b2)+h1; H = relu(h2@Wo+bo)+h2
  gemm4<0, false, 2><<<g4, b256, 0, stream>>>(A0, nullptr, Wp1, b1, nullptr, nullptr, nullptr, A1, nullptr, NN, yb, nys);
  gemm4<1, false, 2><<<g4, b256, 0, stream>>>(A1, nullptr, Wp2, b2, nullptr, nullptr, nullptr, A0, nullptr, NN, yb, nys);
  gemm4<1, false, 2><<<g4, b256, 0, stream>>>(A0, nullptr, Wpo, bo, nullptr, nullptr, nullptr, A1, nullptr, NN, yb, nys);

  // U = H@P1top + P1b -> A0 (UV rows)
  gemm4<3, false, 2><<<g4, b256, 0, stream>>>(A1, nullptr, WpU, P1b, nullptr, nullptr, nullptr, A0, nullptr, NN, yb, nys);
  // V = H@P1bot: 3-buffer path (128-tile) if ws permits, else in-place full-width
  if (use3)
    gemm4<4, false, 2><<<g4, b256, 0, stream>>>(A1, nullptr, WpV, nullptr, nullptr, nullptr, nullptr, A2, nullptr, NN, yb, nys);
  else
    gemm4<4, false, 8><<<gW, b1024, 0, stream>>>(A1, nullptr, WpV, nullptr, nullptr, nullptr, nullptr, A1, nullptr, NN, yb, nys);

  // edges: z1 = relu(U[s]+V[d]) built in-stage; scores = relu(z1@P2+b)@P3 + b3
  gemm4<2, true, 2><<<g4, b256, 0, stream>>>(A0, Vbuf, Wp2p, P2b, P3w, pos_src, pos_dst, nullptr, out, E, yb, nys);
  gemm4<2, true, 2><<<g4, b256, 0, stream>>>(A0, Vbuf, Wp2p, P2b, P3w, neg_src, neg_dst, nullptr, out + E, E, yb, nys);
}

// Round 10
// 3452.147 us; speedup vs baseline: 1.4162x; 1.4162x over previous
//
#include <hip/hip_runtime.h>
#include <stdint.h>

#define HID 512

typedef short bf16x8 __attribute__((ext_vector_type(8)));
typedef short short8v __attribute__((ext_vector_type(8)));
typedef float f32x4 __attribute__((ext_vector_type(4)));

__device__ __forceinline__ unsigned short f2bf_rne(float f) {
  unsigned u = __float_as_uint(f);
  unsigned r = u + 0x7fffu + ((u >> 16) & 1u);
  return (unsigned short)(r >> 16);
}
__device__ __forceinline__ float bf2f(unsigned short u) {
  return __uint_as_float(((unsigned)u) << 16);
}

__device__ __forceinline__ void gload_lds16(const void* g, void* l) {
  auto gp = reinterpret_cast<const __attribute__((address_space(1))) unsigned int*>(
      (unsigned long long)(uintptr_t)g);
  auto lp = reinterpret_cast<__attribute__((address_space(3))) unsigned int*>(
      (unsigned int)(uintptr_t)l);
  __builtin_amdgcn_global_load_lds(gp, lp, 16, 0, 0);
}

// ---------------- pack kernels ----------------
// pack256: W [512 k][512 n] -> [xb2][kt16][pl2][s4][256 n][8 k]  (1 MB)
__global__ void pack256(const float* __restrict__ W, short* __restrict__ out) {
  int id = blockIdx.x * 256 + threadIdx.x;                 // 2^19
  int e = id & 7, r = (id >> 3) & 255, s = (id >> 11) & 3, pl = (id >> 13) & 1,
      kt = (id >> 14) & 15, xb = (id >> 18) & 1;
  int k = kt * 32 + s * 8 + e, n = xb * 256 + r;
  float w = W[(size_t)k * 512 + n];
  unsigned short h = f2bf_rne(w);
  out[id] = pl ? (short)f2bf_rne(w - bf2f(h)) : (short)h;
}

// packW: P1 rows 512..1023 -> [kt16][pl2][s4][512 n][8 k]  (1 MB, full width)
__global__ void packW(const float* __restrict__ P1, short* __restrict__ out) {
  int id = blockIdx.x * 256 + threadIdx.x;                 // 2^19
  int e = id & 7, r = (id >> 3) & 511, s = (id >> 12) & 3, pl = (id >> 14) & 1,
      kt = id >> 15;
  int k = kt * 32 + s * 8 + e;
  float w = P1[(size_t)(512 + k) * 512 + r];
  unsigned short h = f2bf_rne(w);
  out[id] = pl ? (short)f2bf_rne(w - bf2f(h)) : (short)h;
}

// split x -> hi/lo tile image [rb][kt16][pl2][s4][128][8]
__global__ void split_x_img(const float* __restrict__ x, short* __restrict__ img,
                            int NN, int total) {
  int id = blockIdx.x * 256 + threadIdx.x;
  if (id >= total) return;
  int n = id >> 6, kc = id & 63;
  int ns = n < NN ? n : NN - 1;
  const f32x4* xp = reinterpret_cast<const f32x4*>(x + (size_t)ns * 512 + kc * 8);
  f32x4 a = xp[0], b = xp[1];
  short8v h, l;
#pragma unroll
  for (int q = 0; q < 4; ++q) {
    unsigned short ha = f2bf_rne(a[q]);
    h[q] = (short)ha; l[q] = (short)f2bf_rne(a[q] - bf2f(ha));
    unsigned short hb = f2bf_rne(b[q]);
    h[q + 4] = (short)hb; l[q + 4] = (short)f2bf_rne(b[q] - bf2f(hb));
  }
  size_t base = ((size_t)((n >> 7) * 16 + (kc >> 2)) * 2) * 4096 + (kc & 3) * 1024 + (n & 127) * 8;
  *reinterpret_cast<short8v*>(img + base) = h;
  *reinterpret_cast<short8v*>(img + base + 4096) = l;
}

__global__ void init_out_kernel(float* __restrict__ out, const float* __restrict__ p3b, int n) {
  int id = blockIdx.x * 256 + threadIdx.x;
  if (id < n) out[id] = p3b[0];
}

// ---------------- GEMM ----------------
// EPI: 0 relu+bias -> image | 1 relu+bias+residual(global) -> image |
//      2 fused P2 relu + P3 dot -> score | 3 bias, no relu -> UV rows |
//      4 no bias, no relu -> UV rows (wide, in-place safe)
// GATHER: A built in-stage as relu(U[s]+V[d]) from hi/lo UV rows.
// BN_: 256 -> 256-col block, 256 thr, acc[4][8], 2 blocks/CU;
//      512 -> full width, 1024 thr, acc[4][4] (round-8 wide, in-place V).
template <int EPI, bool GATHER, int BN_>
__global__ __launch_bounds__(BN_ == 256 ? 256 : 1024, BN_ == 256 ? 2 : 8) void gemm4(
    const short* A, const short* A2, const short* __restrict__ B,
    const float* __restrict__ bias, const float* __restrict__ p3,
    const int* __restrict__ isrc, const int* __restrict__ idst,
    short* C, float* __restrict__ score, int M, int yb, int nys) {
  constexpr int NJ   = (BN_ == 256) ? 8 : 4;       // B frags per wave
  constexpr int WCW  = (BN_ == 256) ? 128 : 64;    // cols per wave
  constexpr int BSH  = (BN_ == 256) ? 16384 : 32768;  // B lds shorts
  constexpr int SLAB = (BN_ == 256) ? 2048 : 4096;    // B slab stride (shorts)
  constexpr int BPL  = (BN_ == 256) ? 8192 : 16384;   // B plane stride
  __shared__ __align__(16) short lds[8192 + BSH];

  const int tid = threadIdx.x;
  const int lane = tid & 63, wid = tid >> 6;
  const int wr = (BN_ == 256) ? (wid >> 1) : (wid >> 3);
  const int wc = (BN_ == 256) ? (wid & 1) : (wid & 7);
  const int l15 = lane & 15, lh = lane >> 4;

  // XCD swizzle: x-siblings of a y share (g mod 8) -> same XCD
  const int g = blockIdx.x;
  const int xcd = g & 7, rr_ = g >> 3;
  const int x = (BN_ == 256) ? (rr_ & 1) : 0;
  const int slot = (BN_ == 256) ? (rr_ >> 1) : rr_;
  const int y = xcd * nys + slot;
  if (y >= yb) return;
  const int m0 = y << 7;
  const int n0 = x * BN_;

  const size_t aBase0 = (size_t)y * 131072;

  int urow = 0, vrow = 0;
  if constexpr (GATHER) {
    int e = m0 + (tid >> 1); if (e > M - 1) e = M - 1;
    urow = isrc[e]; vrow = idst[e];
  }

  auto stage = [&](int kt) {
    const short* ab = A + aBase0 + (size_t)kt * 8192;
    if constexpr (BN_ == 256) {
#pragma unroll
      for (int p = 0; p < 4; ++p) gload_lds16(ab + p * 2048 + tid * 8, lds + p * 2048 + tid * 8);
      const short* bb = B + (size_t)(x * 16 + kt) * 16384;
#pragma unroll
      for (int p = 0; p < 8; ++p) gload_lds16(bb + p * 2048 + tid * 8, lds + 8192 + p * 2048 + tid * 8);
    } else {
      gload_lds16(ab + tid * 8, lds + tid * 8);
      const short* bb = B + (size_t)kt * 32768;
#pragma unroll
      for (int p = 0; p < 4; ++p) gload_lds16(bb + p * 8192 + tid * 8, lds + 8192 + p * 8192 + tid * 8);
    }
  };

  auto stageG = [&](int kt) {
    const short* bb = B + (size_t)(x * 16 + kt) * 16384;
#pragma unroll
    for (int p = 0; p < 8; ++p) gload_lds16(bb + p * 2048 + tid * 8, lds + 8192 + p * 2048 + tid * 8);
    const int kh = tid & 1;
    const size_t ub = (size_t)(urow >> 7) * 131072 + (urow & 127) * 1024 + kt * 32 + kh * 16;
    const size_t vb = (size_t)(vrow >> 7) * 131072 + (vrow & 127) * 1024 + kt * 32 + kh * 16;
    short8v uh0 = *(const short8v*)(A + ub),        uh1 = *(const short8v*)(A + ub + 8);
    short8v ul0 = *(const short8v*)(A + ub + 512),  ul1 = *(const short8v*)(A + ub + 520);
    short8v vh0 = *(const short8v*)(A2 + vb),       vh1 = *(const short8v*)(A2 + vb + 8);
    short8v vl0 = *(const short8v*)(A2 + vb + 512), vl1 = *(const short8v*)(A2 + vb + 520);
    short8v zh0, zh1, zl0, zl1;
#pragma unroll
    for (int q = 0; q < 8; ++q) {
      float u0 = bf2f((unsigned short)uh0[q]) + bf2f((unsigned short)ul0[q]);
      float v0 = bf2f((unsigned short)vh0[q]) + bf2f((unsigned short)vl0[q]);
      float z0 = fmaxf(u0 + v0, 0.f);
      unsigned zb0 = __float_as_uint(z0);
      zh0[q] = (short)(zb0 >> 16);
      zl0[q] = (short)f2bf_rne(z0 - __uint_as_float(zb0 & 0xffff0000u));
      float u1 = bf2f((unsigned short)uh1[q]) + bf2f((unsigned short)ul1[q]);
      float v1 = bf2f((unsigned short)vh1[q]) + bf2f((unsigned short)vl1[q]);
      float z1 = fmaxf(u1 + v1, 0.f);
      unsigned zb1 = __float_as_uint(z1);
      zh1[q] = (short)(zb1 >> 16);
      zl1[q] = (short)f2bf_rne(z1 - __uint_as_float(zb1 & 0xffff0000u));
    }
    const int da = kh * 2048 + (tid >> 1) * 8;   // [s=2kh(+1)][r][8]
    *reinterpret_cast<short8v*>(lds + da) = zh0;
    *reinterpret_cast<short8v*>(lds + da + 1024) = zh1;
    *reinterpret_cast<short8v*>(lds + 4096 + da) = zl0;
    *reinterpret_cast<short8v*>(lds + 4096 + da + 1024) = zl1;
  };

  f32x4 acc[4][NJ];
#pragma unroll
  for (int i = 0; i < 4; ++i)
#pragma unroll
    for (int j = 0; j < NJ; ++j)
#pragma unroll
      for (int r = 0; r < 4; ++r) acc[i][j][r] = 0.f;

  auto compute = [&]() {
    bf16x8 ah[4], al[4];
#pragma unroll
    for (int i = 0; i < 4; ++i) {
      const int ro = lh * 1024 + (wr * 64 + i * 16 + l15) * 8;
      ah[i] = *reinterpret_cast<const bf16x8*>(lds + ro);
      al[i] = *reinterpret_cast<const bf16x8*>(lds + 4096 + ro);
    }
#pragma unroll
    for (int j = 0; j < NJ; ++j) {
      const int co = 8192 + lh * SLAB + (wc * WCW + j * 16 + l15) * 8;
      bf16x8 bh = *reinterpret_cast<const bf16x8*>(lds + co);
      bf16x8 bl = *reinterpret_cast<const bf16x8*>(lds + co + BPL);
#pragma unroll
      for (int i = 0; i < 4; ++i) {
        acc[i][j] = __builtin_amdgcn_mfma_f32_16x16x32_bf16(ah[i], bh, acc[i][j], 0, 0, 0);
        acc[i][j] = __builtin_amdgcn_mfma_f32_16x16x32_bf16(ah[i], bl, acc[i][j], 0, 0, 0);
        acc[i][j] = __builtin_amdgcn_mfma_f32_16x16x32_bf16(al[i], bh, acc[i][j], 0, 0, 0);
      }
    }
  };

  // K-loop: single buffer, 2 barriers per step; co-resident blocks hide drains
  for (int kt = 0; kt < 16; ++kt) {
    if (kt) __syncthreads();
    if constexpr (GATHER) stageG(kt); else stage(kt);
    __syncthreads();
    compute();
  }

  // ---------------- epilogue ----------------
  float bj[NJ], pj[NJ];
#pragma unroll
  for (int j = 0; j < NJ; ++j) {
    const int col = n0 + wc * WCW + j * 16 + l15;
    bj[j] = (EPI == 4) ? 0.f : bias[col];
    pj[j] = (EPI == 2) ? p3[col] : 0.f;
  }

  if constexpr (EPI == 2) {
#pragma unroll
    for (int fi = 0; fi < 4; ++fi)
#pragma unroll
      for (int r = 0; r < 4; ++r) {
        float pS = 0.f;
#pragma unroll
        for (int fj = 0; fj < NJ; ++fj)
          pS += fmaxf(acc[fi][fj][r] + bj[fj], 0.f) * pj[fj];
        pS += __shfl_xor(pS, 1);
        pS += __shfl_xor(pS, 2);
        pS += __shfl_xor(pS, 4);
        pS += __shfl_xor(pS, 8);
        const int row = m0 + wr * 64 + fi * 16 + lh * 4 + r;
        if (l15 == 0 && row < M) atomicAdd(&score[row], pS);
      }
  } else {
#pragma unroll
    for (int fi = 0; fi < 4; ++fi)
#pragma unroll
      for (int fj = 0; fj < NJ; ++fj) {
        const int col = n0 + wc * WCW + fj * 16 + l15;
#pragma unroll
        for (int r = 0; r < 4; ++r) {
          const int row = m0 + wr * 64 + fi * 16 + lh * 4 + r;
          if (row >= M) continue;
          float v = acc[fi][fj][r] + bj[fj];
          if constexpr (EPI == 0 || EPI == 1) v = fmaxf(v, 0.f);
          if constexpr (EPI == 0 || EPI == 1) {
            const size_t ix = ((size_t)(y * 16 + (col >> 5)) * 2) * 4096 +
                              ((col >> 3) & 3) * 1024 + (row & 127) * 8 + (col & 7);
            if constexpr (EPI == 1)
              v += bf2f((unsigned short)A[ix]) + bf2f((unsigned short)A[ix + 4096]);
            unsigned short h = f2bf_rne(v);
            C[ix] = (short)h;
            C[ix + 4096] = (short)f2bf_rne(v - bf2f(h));
          } else {  // EPI 3/4: UV row layout [rb][r][hi512|lo512]
            const size_t ux = (size_t)y * 131072 + (row & 127) * 1024 + col;
            unsigned short h = f2bf_rne(v);
            C[ux] = (short)h;
            C[ux + 512] = (short)f2bf_rne(v - bf2f(h));
          }
        }
      }
  }
}

extern "C" void kernel_launch(void* const* d_in, const int* in_sizes, int n_in,
                              void* d_out, int out_size, void* d_ws, size_t ws_size,
                              hipStream_t stream) {
  (void)n_in; (void)out_size; (void)ws_size;
  const float* x      = (const float*)d_in[0];
  const int* pos_src  = (const int*)d_in[1];
  const int* pos_dst  = (const int*)d_in[2];
  const int* neg_src  = (const int*)d_in[3];
  const int* neg_dst  = (const int*)d_in[4];
  const float* W1 = (const float*)d_in[5];
  const float* b1 = (const float*)d_in[6];
  const float* W2 = (const float*)d_in[7];
  const float* b2 = (const float*)d_in[8];
  const float* Wo = (const float*)d_in[9];
  const float* bo = (const float*)d_in[10];
  const float* P1w = (const float*)d_in[11];
  const float* P1b = (const float*)d_in[12];
  const float* P2w = (const float*)d_in[13];
  const float* P2b = (const float*)d_in[14];
  const float* P3w = (const float*)d_in[15];
  const float* P3b = (const float*)d_in[16];

  const int NN = in_sizes[0] / HID;  // 100000
  const int E = in_sizes[1];         // 100000
  float* out = (float*)d_out;

  const int yb = (NN + 127) / 128;           // 782 (== (E+127)/128)
  const int nys = (yb + 7) / 8;              // 98
  const size_t IMG = (size_t)yb * 131072;    // shorts per activation buffer

  // ws layout: [6 weight packs 1MB each][A0][A1]
  short* wp = (short*)d_ws;
  short* Wp1  = wp; wp += 524288;
  short* Wp2  = wp; wp += 524288;
  short* Wpo  = wp; wp += 524288;
  short* Wp2p = wp; wp += 524288;
  short* WpU  = wp; wp += 524288;            // P1 top (xb2 images)
  short* WpV  = wp; wp += 524288;            // P1 bottom (wide image)
  short* A0 = wp;                            // x-img -> h2-img -> U (UV rows)
  short* A1 = A0 + IMG;                      // h1-img -> H-img -> V (UV rows, in place)

  pack256<<<2048, 256, 0, stream>>>(W1, Wp1);
  pack256<<<2048, 256, 0, stream>>>(W2, Wp2);
  pack256<<<2048, 256, 0, stream>>>(Wo, Wpo);
  pack256<<<2048, 256, 0, stream>>>(P2w, Wp2p);
  pack256<<<2048, 256, 0, stream>>>(P1w, WpU);
  packW<<<2048, 256, 0, stream>>>(P1w, WpV);
  const int totX = yb * 128 * 64;
  split_x_img<<<(totX + 255) / 256, 256, 0, stream>>>(x, A0, NN, totX);
  init_out_kernel<<<(2 * E + 255) / 256, 256, 0, stream>>>(out, P3b, 2 * E);

  dim3 g2(8 * nys * 2), gW(8 * nys), b256(256), b1024(1024);

  // encoder: h1 = relu(x@W1+b1); h2 = relu(h1@W2+b2)+h1; H = relu(h2@Wo+bo)+h2
  gemm4<0, false, 256><<<g2, b256, 0, stream>>>(A0, nullptr, Wp1, b1, nullptr, nullptr, nullptr, A1, nullptr, NN, yb, nys);
  gemm4<1, false, 256><<<g2, b256, 0, stream>>>(A1, nullptr, Wp2, b2, nullptr, nullptr, nullptr, A0, nullptr, NN, yb, nys);
  gemm4<1, false, 256><<<g2, b256, 0, stream>>>(A0, nullptr, Wpo, bo, nullptr, nullptr, nullptr, A1, nullptr, NN, yb, nys);

  // U = H@P1top + P1b -> A0 (UV rows)
  gemm4<3, false, 256><<<g2, b256, 0, stream>>>(A1, nullptr, WpU, P1b, nullptr, nullptr, nullptr, A0, nullptr, NN, yb, nys);
  // V = H@P1bot -> A1 in place (wide block owns its rows exclusively)
  gemm4<4, false, 512><<<gW, b1024, 0, stream>>>(A1, nullptr, WpV, nullptr, nullptr, nullptr, nullptr, A1, nullptr, NN, yb, nys);

  // edges: z1 = relu(U[s]+V[d]) built in-stage; scores = relu(z1@P2+b)@P3 + b3
  gemm4<2, true, 256><<<g2, b256, 0, stream>>>(A0, A1, Wp2p, P2b, P3w, pos_src, pos_dst, nullptr, out, E, yb, nys);
  gemm4<2, true, 256><<<g2, b256, 0, stream>>>(A0, A1, Wp2p, P2b, P3w, neg_src, neg_dst, nullptr, out + E, E, yb, nys);
}

// Round 11
// 1477.664 us; speedup vs baseline: 3.3084x; 2.3362x over previous
//
#include <hip/hip_runtime.h>
#include <stdint.h>

#define HID 512

typedef short bf16x8 __attribute__((ext_vector_type(8)));
typedef short short8v __attribute__((ext_vector_type(8)));
typedef float f32x4 __attribute__((ext_vector_type(4)));

__device__ __forceinline__ unsigned short f2bf_rne(float f) {
  unsigned u = __float_as_uint(f);
  unsigned r = u + 0x7fffu + ((u >> 16) & 1u);
  return (unsigned short)(r >> 16);
}
__device__ __forceinline__ float bf2f(unsigned short u) {
  return __uint_as_float(((unsigned)u) << 16);
}

__device__ __forceinline__ void gload_lds16(const void* g, void* l) {
  auto gp = reinterpret_cast<const __attribute__((address_space(1))) unsigned int*>(
      (unsigned long long)(uintptr_t)g);
  auto lp = reinterpret_cast<__attribute__((address_space(3))) unsigned int*>(
      (unsigned int)(uintptr_t)l);
  __builtin_amdgcn_global_load_lds(gp, lp, 16, 0, 0);
}

// ---------------- pack kernels ----------------
// pack4: W [512 k][512 n] -> [xb4][kt16][pl2][s4][128 n][8 k]  (1 MB)
__global__ void pack4(const float* __restrict__ W, short* __restrict__ out) {
  int id = blockIdx.x * 256 + threadIdx.x;                 // 2^19
  int e = id & 7, r = (id >> 3) & 127, s = (id >> 10) & 3, pl = (id >> 12) & 1,
      kt = (id >> 13) & 15, xb = id >> 17;
  int k = kt * 32 + s * 8 + e, n = xb * 128 + r;
  float w = W[(size_t)k * 512 + n];
  unsigned short h = f2bf_rne(w);
  out[id] = pl ? (short)f2bf_rne(w - bf2f(h)) : (short)h;
}

// packW: P1 rows 512..1023 -> [kt16][pl2][s4][512 n][8 k]  (1 MB, full width)
__global__ void packW(const float* __restrict__ P1, short* __restrict__ out) {
  int id = blockIdx.x * 256 + threadIdx.x;                 // 2^19
  int e = id & 7, r = (id >> 3) & 511, s = (id >> 12) & 3, pl = (id >> 14) & 1,
      kt = id >> 15;
  int k = kt * 32 + s * 8 + e;
  float w = P1[(size_t)(512 + k) * 512 + r];
  unsigned short h = f2bf_rne(w);
  out[id] = pl ? (short)f2bf_rne(w - bf2f(h)) : (short)h;
}

__global__ void init_out_kernel(float* __restrict__ out, const float* __restrict__ p3b, int n) {
  int id = blockIdx.x * 256 + threadIdx.x;
  if (id < n) out[id] = p3b[0];
}

// ---------------- GEMM ----------------
// EPI: 0 relu+bias -> image | 1 relu+bias+residual(global re-read) -> image |
//      2 fused P2 relu + P3 dot -> score | 3 bias, no relu -> UV rows |
//      4 no bias, no relu -> UV rows (wide, in-place safe)
// GATHER: A built in-stage as relu(U[s]+V[d]) from hi/lo UV rows.
// AF32: A staged from fp32 source (truncation hi / RNE lo split in-loop).
// WN: 2 -> 128-col block, 256 thr, 4 blocks/CU; 8 -> 512-col, 1024 thr, 1 blk/CU.
template <int EPI, bool GATHER, int WN, bool AF32>
__global__ __launch_bounds__(WN * 128, 4) void gemm4(
    const float* __restrict__ Af32,
    const short* A, const short* A2, const short* __restrict__ B,
    const float* __restrict__ bias, const float* __restrict__ p3,
    const int* __restrict__ isrc, const int* __restrict__ idst,
    short* C, float* __restrict__ score, int M, int yb, int nys) {
  constexpr int BSH = 4096 * WN;            // B lds shorts (8192 / 32768)
  constexpr int BSTR = 512 * WN;            // B slab stride (1024 / 4096)
  constexpr int BPL = 2048 * WN;            // B plane stride (4096 / 16384)
  __shared__ __align__(16) short lds[8192 + BSH];

  const int tid = threadIdx.x;
  const int lane = tid & 63, wid = tid >> 6;
  const int wr = (WN == 2) ? (wid >> 1) : (wid >> 3);
  const int wc = (WN == 2) ? (wid & 1) : (wid & 7);
  const int l15 = lane & 15, lh = lane >> 4;

  // XCD swizzle: x-siblings of a y share (g mod 8) -> same XCD; y streams per XCD
  const int g = blockIdx.x;
  const int xcd = g & 7, rr_ = g >> 3;
  const int x = (WN == 2) ? (rr_ & 3) : 0;
  const int slot = (WN == 2) ? (rr_ >> 2) : rr_;
  const int y = xcd * nys + slot;
  if (y >= yb) return;
  const int m0 = y << 7;
  const int n0 = x << 7;

  const size_t aBase0 = (size_t)y * 131072;

  int urow = 0, vrow = 0;
  if constexpr (GATHER) {
    int e = m0 + (tid >> 1); if (e > M - 1) e = M - 1;
    urow = isrc[e]; vrow = idst[e];
  }
  const float* gxBase = nullptr;
  if constexpr (AF32) {
    int r = m0 + (tid >> 1); if (r > M - 1) r = M - 1;
    gxBase = Af32 + (size_t)r * HID + (tid & 1) * 16;
  }

  auto stage = [&](int kt) {
    // ---- A ----
    if constexpr (AF32) {
      const float* gx = gxBase + kt * 32;
      const int r = tid >> 1, hf = tid & 1;
#pragma unroll
      for (int c = 0; c < 2; ++c) {
        f32x4 v0 = *reinterpret_cast<const f32x4*>(gx + c * 8);
        f32x4 v1 = *reinterpret_cast<const f32x4*>(gx + c * 8 + 4);
        short8v h, l;
#pragma unroll
        for (int q = 0; q < 4; ++q) {
          unsigned ua = __float_as_uint(v0[q]);
          h[q] = (short)(ua >> 16);
          l[q] = (short)f2bf_rne(v0[q] - __uint_as_float(ua & 0xffff0000u));
          unsigned ub = __float_as_uint(v1[q]);
          h[q + 4] = (short)(ub >> 16);
          l[q + 4] = (short)f2bf_rne(v1[q] - __uint_as_float(ub & 0xffff0000u));
        }
        const int da = (hf * 2 + c) * 1024 + r * 8;
        *reinterpret_cast<short8v*>(lds + da) = h;
        *reinterpret_cast<short8v*>(lds + 4096 + da) = l;
      }
    } else {
      const short* ab = A + aBase0 + (size_t)kt * 8192;
      if constexpr (WN == 2) {
#pragma unroll
        for (int p = 0; p < 4; ++p)
          gload_lds16(ab + p * 2048 + tid * 8, lds + p * 2048 + tid * 8);
      } else {
        gload_lds16(ab + tid * 8, lds + tid * 8);
      }
    }
    // ---- B ----
    const short* bb = B + (size_t)((WN == 2) ? (x * 16 + kt) : kt) * BSH;
    if constexpr (WN == 2) {
#pragma unroll
      for (int p = 0; p < 4; ++p)
        gload_lds16(bb + p * 2048 + tid * 8, lds + 8192 + p * 2048 + tid * 8);
    } else {
#pragma unroll
      for (int p = 0; p < 4; ++p)
        gload_lds16(bb + p * 8192 + tid * 8, lds + 8192 + p * 8192 + tid * 8);
    }
  };

  auto stageG = [&](int kt) {
    const short* bb = B + (size_t)(x * 16 + kt) * 8192;
#pragma unroll
    for (int p = 0; p < 4; ++p)
      gload_lds16(bb + p * 2048 + tid * 8, lds + 8192 + p * 2048 + tid * 8);
    const int kh = tid & 1;
    const size_t ub = (size_t)(urow >> 7) * 131072 + (urow & 127) * 1024 + kt * 32 + kh * 16;
    const size_t vb = (size_t)(vrow >> 7) * 131072 + (vrow & 127) * 1024 + kt * 32 + kh * 16;
    short8v uh0 = *(const short8v*)(A + ub),        uh1 = *(const short8v*)(A + ub + 8);
    short8v ul0 = *(const short8v*)(A + ub + 512),  ul1 = *(const short8v*)(A + ub + 520);
    short8v vh0 = *(const short8v*)(A2 + vb),       vh1 = *(const short8v*)(A2 + vb + 8);
    short8v vl0 = *(const short8v*)(A2 + vb + 512), vl1 = *(const short8v*)(A2 + vb + 520);
    short8v zh0, zh1, zl0, zl1;
#pragma unroll
    for (int q = 0; q < 8; ++q) {
      float u0 = bf2f((unsigned short)uh0[q]) + bf2f((unsigned short)ul0[q]);
      float v0 = bf2f((unsigned short)vh0[q]) + bf2f((unsigned short)vl0[q]);
      float z0 = fmaxf(u0 + v0, 0.f);
      unsigned zb0 = __float_as_uint(z0);
      zh0[q] = (short)(zb0 >> 16);
      zl0[q] = (short)f2bf_rne(z0 - __uint_as_float(zb0 & 0xffff0000u));
      float u1 = bf2f((unsigned short)uh1[q]) + bf2f((unsigned short)ul1[q]);
      float v1 = bf2f((unsigned short)vh1[q]) + bf2f((unsigned short)vl1[q]);
      float z1 = fmaxf(u1 + v1, 0.f);
      unsigned zb1 = __float_as_uint(z1);
      zh1[q] = (short)(zb1 >> 16);
      zl1[q] = (short)f2bf_rne(z1 - __uint_as_float(zb1 & 0xffff0000u));
    }
    const int da = kh * 2048 + (tid >> 1) * 8;   // [s=2kh(+1)][r][8]
    *reinterpret_cast<short8v*>(lds + da) = zh0;
    *reinterpret_cast<short8v*>(lds + da + 1024) = zh1;
    *reinterpret_cast<short8v*>(lds + 4096 + da) = zl0;
    *reinterpret_cast<short8v*>(lds + 4096 + da + 1024) = zl1;
  };

  f32x4 acc[4][4];
#pragma unroll
  for (int i = 0; i < 4; ++i)
#pragma unroll
    for (int j = 0; j < 4; ++j)
#pragma unroll
      for (int r = 0; r < 4; ++r) acc[i][j][r] = 0.f;

  auto compute = [&]() {
    bf16x8 ah[4], al[4];
#pragma unroll
    for (int i = 0; i < 4; ++i) {
      const int ro = lh * 1024 + (wr * 64 + i * 16 + l15) * 8;
      ah[i] = *reinterpret_cast<const bf16x8*>(lds + ro);
      al[i] = *reinterpret_cast<const bf16x8*>(lds + 4096 + ro);
    }
#pragma unroll
    for (int j = 0; j < 4; ++j) {
      const int co = 8192 + lh * BSTR + (wc * 64 + j * 16 + l15) * 8;
      bf16x8 bh = *reinterpret_cast<const bf16x8*>(lds + co);
      bf16x8 bl = *reinterpret_cast<const bf16x8*>(lds + co + BPL);
#pragma unroll
      for (int i = 0; i < 4; ++i) {
        acc[i][j] = __builtin_amdgcn_mfma_f32_16x16x32_bf16(ah[i], bh, acc[i][j], 0, 0, 0);
        acc[i][j] = __builtin_amdgcn_mfma_f32_16x16x32_bf16(ah[i], bl, acc[i][j], 0, 0, 0);
        acc[i][j] = __builtin_amdgcn_mfma_f32_16x16x32_bf16(al[i], bh, acc[i][j], 0, 0, 0);
      }
    }
  };

  // K-loop: single buffer, 2 barriers per step; co-resident blocks hide drains
  for (int kt = 0; kt < 16; ++kt) {
    if (kt) __syncthreads();
    if constexpr (GATHER) stageG(kt); else stage(kt);
    __syncthreads();
    compute();
  }

  // ---------------- epilogue ----------------
  float bj[4], pj[4];
#pragma unroll
  for (int j = 0; j < 4; ++j) {
    const int col = n0 + wc * 64 + j * 16 + l15;
    bj[j] = (EPI == 4) ? 0.f : bias[col];
    pj[j] = (EPI == 2) ? p3[col] : 0.f;
  }

  if constexpr (EPI == 2) {
#pragma unroll
    for (int fi = 0; fi < 4; ++fi)
#pragma unroll
      for (int r = 0; r < 4; ++r) {
        float pS = 0.f;
#pragma unroll
        for (int fj = 0; fj < 4; ++fj)
          pS += fmaxf(acc[fi][fj][r] + bj[fj], 0.f) * pj[fj];
        pS += __shfl_xor(pS, 1);
        pS += __shfl_xor(pS, 2);
        pS += __shfl_xor(pS, 4);
        pS += __shfl_xor(pS, 8);
        const int row = m0 + wr * 64 + fi * 16 + lh * 4 + r;
        if (l15 == 0 && row < M) atomicAdd(&score[row], pS);
      }
  } else {
#pragma unroll
    for (int fi = 0; fi < 4; ++fi)
#pragma unroll
      for (int fj = 0; fj < 4; ++fj) {
        const int col = n0 + wc * 64 + fj * 16 + l15;
#pragma unroll
        for (int r = 0; r < 4; ++r) {
          const int row = m0 + wr * 64 + fi * 16 + lh * 4 + r;
          if (row >= M) continue;
          float v = acc[fi][fj][r] + bj[fj];
          if constexpr (EPI == 0 || EPI == 1) v = fmaxf(v, 0.f);
          if constexpr (EPI == 0 || EPI == 1) {
            const size_t ix = ((size_t)(y * 16 + (col >> 5)) * 2) * 4096 +
                              ((col >> 3) & 3) * 1024 + (row & 127) * 8 + (col & 7);
            if constexpr (EPI == 1)
              v += bf2f((unsigned short)A[ix]) + bf2f((unsigned short)A[ix + 4096]);
            unsigned short h = f2bf_rne(v);
            C[ix] = (short)h;
            C[ix + 4096] = (short)f2bf_rne(v - bf2f(h));
          } else {  // EPI 3/4: UV row layout [rb][r][hi512|lo512]
            const size_t ux = (size_t)y * 131072 + (row & 127) * 1024 + col;
            unsigned short h = f2bf_rne(v);
            C[ux] = (short)h;
            C[ux + 512] = (short)f2bf_rne(v - bf2f(h));
          }
        }
      }
  }
}

extern "C" void kernel_launch(void* const* d_in, const int* in_sizes, int n_in,
                              void* d_out, int out_size, void* d_ws, size_t ws_size,
                              hipStream_t stream) {
  (void)n_in; (void)out_size; (void)ws_size;
  const float* x      = (const float*)d_in[0];
  const int* pos_src  = (const int*)d_in[1];
  const int* pos_dst  = (const int*)d_in[2];
  const int* neg_src  = (const int*)d_in[3];
  const int* neg_dst  = (const int*)d_in[4];
  const float* W1 = (const float*)d_in[5];
  const float* b1 = (const float*)d_in[6];
  const float* W2 = (const float*)d_in[7];
  const float* b2 = (const float*)d_in[8];
  const float* Wo = (const float*)d_in[9];
  const float* bo = (const float*)d_in[10];
  const float* P1w = (const float*)d_in[11];
  const float* P1b = (const float*)d_in[12];
  const float* P2w = (const float*)d_in[13];
  const float* P2b = (const float*)d_in[14];
  const float* P3w = (const float*)d_in[15];
  const float* P3b = (const float*)d_in[16];

  const int NN = in_sizes[0] / HID;  // 100000
  const int E = in_sizes[1];         // 100000
  float* out = (float*)d_out;

  const int yb = (NN + 127) / 128;           // 782 (== (E+127)/128)
  const int nys = (yb + 7) / 8;              // 98
  const size_t IMG = (size_t)yb * 131072;    // shorts per activation buffer

  // ws layout: [6 weight packs 1MB each][A0][A1]
  short* wp = (short*)d_ws;
  short* Wp1  = wp; wp += 524288;
  short* Wp2  = wp; wp += 524288;
  short* Wpo  = wp; wp += 524288;
  short* Wp2p = wp; wp += 524288;
  short* WpU  = wp; wp += 524288;            // P1 top (xb4 images)
  short* WpV  = wp; wp += 524288;            // P1 bottom (wide image)
  short* A0 = wp;                            // h2-img -> U (UV rows)
  short* A1 = A0 + IMG;                      // h1-img -> H-img -> V (UV rows, in place)

  pack4<<<2048, 256, 0, stream>>>(W1, Wp1);
  pack4<<<2048, 256, 0, stream>>>(W2, Wp2);
  pack4<<<2048, 256, 0, stream>>>(Wo, Wpo);
  pack4<<<2048, 256, 0, stream>>>(P2w, Wp2p);
  pack4<<<2048, 256, 0, stream>>>(P1w, WpU);
  packW<<<2048, 256, 0, stream>>>(P1w, WpV);
  init_out_kernel<<<(2 * E + 255) / 256, 256, 0, stream>>>(out, P3b, 2 * E);

  dim3 g4(8 * nys * 4), gW(8 * nys), b256(256), b1024(1024);

  // encoder: h1 = relu(x@W1+b1) (x split in-stage); h2 = relu(h1@W2+b2)+h1;
  //          H = relu(h2@Wo+bo)+h2
  gemm4<0, false, 2, true><<<g4, b256, 0, stream>>>(x, nullptr, nullptr, Wp1, b1, nullptr, nullptr, nullptr, A1, nullptr, NN, yb, nys);
  gemm4<1, false, 2, false><<<g4, b256, 0, stream>>>(nullptr, A1, nullptr, Wp2, b2, nullptr, nullptr, nullptr, A0, nullptr, NN, yb, nys);
  gemm4<1, false, 2, false><<<g4, b256, 0, stream>>>(nullptr, A0, nullptr, Wpo, bo, nullptr, nullptr, nullptr, A1, nullptr, NN, yb, nys);

  // U = H@P1top + P1b -> A0 (UV rows)
  gemm4<3, false, 2, false><<<g4, b256, 0, stream>>>(nullptr, A1, nullptr, WpU, P1b, nullptr, nullptr, nullptr, A0, nullptr, NN, yb, nys);
  // V = H@P1bot -> A1 in place (wide block owns its rows exclusively; 1 blk/CU, spill-proof)
  gemm4<4, false, 8, false><<<gW, b1024, 0, stream>>>(nullptr, A1, nullptr, WpV, nullptr, nullptr, nullptr, nullptr, A1, nullptr, NN, yb, nys);

  // edges: z1 = relu(U[s]+V[d]) built in-stage; scores = relu(z1@P2+b)@P3 + b3
  gemm4<2, true, 2, false><<<g4, b256, 0, stream>>>(nullptr, A0, A1, Wp2p, P2b, P3w, pos_src, pos_dst, nullptr, out, E, yb, nys);
  gemm4<2, true, 2, false><<<g4, b256, 0, stream>>>(nullptr, A0, A1, Wp2p, P2b, P3w, neg_src, neg_dst, nullptr, out + E, E, yb, nys);
}